// Round 14
// baseline (234.409 us; speedup 1.0000x reference)
//
#include <hip/hip_runtime.h>

#define N_NODES 10000
#define N_EDGES 160000
#define FEAT 512
#define M_PAD 10048        // 157 * 64  (GEMM BM=64)
#define QSTRIDE 1286144    // xs quarter stride in halves: 10048 * 128

typedef unsigned int uint32;

typedef __attribute__((ext_vector_type(8))) _Float16 half8;     // 16 B = MFMA A/B frag
typedef __attribute__((ext_vector_type(4))) float f32x4;        // MFMA C/D

// ---- tiled ("fragment order") fp16 layout for a R x 512 matrix ----
// strip s = row>>4 (16 rows), k-block kb = k>>5 (32 k). Each (s,kb) is a 1 KB
// tile; half-elem offset = s*8192 + kb*512 + (kq*16 + (row&15))*8 + (k&7),
// kq = (k>>3)&3.
//
// ---- quarter-major xs layout (gather source) ----
// xs[q*QSTRIDE + node*128 + f], q = feat>>7, f = feat&127. Agg pins quarter q
// to XCD pair {2q, 2q+1}.
//
// Config ledger (measured totals): R13 = 234.1 (best, this base + BK=64);
// R11 = 235.3; R6 = 236.0; R7 = 238.1; R12 GEMM-dbuf = 240.3 (compiler
// drains vmcnt(0) at every barrier -> no overlap); R10 BN=64 = 246.3.
// R9 probe: agg = VALU/issue-bound-ish (50% VALU, 8.7% HBM); fma_mix (R13)
// gave only -1.2 -> stalls are addressing/divergence/latency, not acc issue.
// R8 probe: GEMM ~600ns/K-iter = serial stage round trip, 16x per block ->
// this round: BK=64 halves the round-trip count (16 -> 8 iters).

__device__ __forceinline__ void load_lds16(const void* g, void* l) {
    __builtin_amdgcn_global_load_lds(
        (const __attribute__((address_space(1))) void*)g,
        (__attribute__((address_space(3))) void*)l, 16, 0, 0);
}

// acc[i] += f16[i] for 8 packed halves in a uint4, one v_fma_mix_f32 each.
__device__ __forceinline__ void acc_mix(float (&acc)[8], uint4 u, float one) {
    asm("v_fma_mix_f32 %0, %8, %9, %0 op_sel_hi:[1,0,0]\n\t"
        "v_fma_mix_f32 %1, %8, %9, %1 op_sel:[1,0,0] op_sel_hi:[1,0,0]\n\t"
        "v_fma_mix_f32 %2, %10, %9, %2 op_sel_hi:[1,0,0]\n\t"
        "v_fma_mix_f32 %3, %10, %9, %3 op_sel:[1,0,0] op_sel_hi:[1,0,0]\n\t"
        "v_fma_mix_f32 %4, %11, %9, %4 op_sel_hi:[1,0,0]\n\t"
        "v_fma_mix_f32 %5, %11, %9, %5 op_sel:[1,0,0] op_sel_hi:[1,0,0]\n\t"
        "v_fma_mix_f32 %6, %12, %9, %6 op_sel_hi:[1,0,0]\n\t"
        "v_fma_mix_f32 %7, %12, %9, %7 op_sel:[1,0,0] op_sel_hi:[1,0,0]"
        : "+v"(acc[0]), "+v"(acc[1]), "+v"(acc[2]), "+v"(acc[3]),
          "+v"(acc[4]), "+v"(acc[5]), "+v"(acc[6]), "+v"(acc[7])
        : "v"(u.x), "v"(one), "v"(u.y), "v"(u.z), "v"(u.w));
}

// ---------------- degree count ----------------
__global__ void deg_kernel(const int* __restrict__ src, const int* __restrict__ dst,
                           int* __restrict__ deg_out, int* __restrict__ deg_in) {
    int e = blockIdx.x * blockDim.x + threadIdx.x;
    if (e < N_EDGES) {
        atomicAdd(&deg_out[src[e]], 1);
        atomicAdd(&deg_in[dst[e]], 1);
    }
}

// ---------------- scan phase 1: per-block exclusive scan + norms ----------------
__global__ __launch_bounds__(256) void scan1_kernel(const int* __restrict__ deg_in,
        const int* __restrict__ deg_out, int* __restrict__ row_ptr,
        int* __restrict__ bsum, float* __restrict__ norm_out, float* __restrict__ norm_in) {
    __shared__ int s[256];
    int t = threadIdx.x, b = blockIdx.x;
    int i = b * 256 + t;
    int v = (i < N_NODES) ? deg_in[i] : 0;
    s[t] = v;
    __syncthreads();
    for (int off = 1; off < 256; off <<= 1) {
        int x = (t >= off) ? s[t - off] : 0;
        __syncthreads();
        s[t] += x;
        __syncthreads();
    }
    if (i < N_NODES) {
        row_ptr[i] = s[t] - v;                 // block-local exclusive prefix
        int dob = deg_out[i];
        norm_in[i]  = v   > 0 ? rsqrtf((float)v)   : 0.f;
        norm_out[i] = dob > 0 ? rsqrtf((float)dob) : 0.f;
    }
    if (t == 255) bsum[b] = s[255];
}

// ---------------- scan phase 2: add block offsets ----------------
__global__ __launch_bounds__(256) void scan2_kernel(const int* __restrict__ bsum,
        int* __restrict__ row_ptr, int* __restrict__ cursor) {
    int t = threadIdx.x, b = blockIdx.x;
    int i = b * 256 + t;
    int off = 0;
    for (int j = 0; j < b; j++) off += bsum[j];   // uniform, <=39 L2-hot scalar loads
    if (i < N_NODES) {
        int r = row_ptr[i] + off;
        row_ptr[i] = r;
        cursor[i] = r;
    }
    if (b == 0 && t == 0) row_ptr[N_NODES] = N_EDGES;   // degrees sum to edge count
}

// ---------------- CSR fill ----------------
__global__ void fill_kernel(const int* __restrict__ src, const int* __restrict__ dst,
                            int* __restrict__ cursor, int* __restrict__ edge_src) {
    int e = blockIdx.x * blockDim.x + threadIdx.x;
    if (e < N_EDGES) {
        int d = dst[e];
        int pos = atomicAdd(&cursor[d], 1);
        edge_src[pos] = src[e];
    }
}

// ---------------- merged prep: prescale (blocks 0..2499) + wsplit (2500..2883) ----------------
__global__ __launch_bounds__(256) void prep_kernel(const float* __restrict__ x,
        const float* __restrict__ norm_out, _Float16* __restrict__ xs,
        const float* __restrict__ W1, const float* __restrict__ W2,
        const float* __restrict__ W3, _Float16* __restrict__ wt) {
    int bid = blockIdx.x;
    if (bid < 2500) {
        int idx = bid * 256 + threadIdx.x;        // one per 8 floats; 2500*256 = 640000 exact
        int node = idx >> 6, f8 = idx & 63;
        float w = norm_out[node];
        const float4* p = (const float4*)&x[(size_t)node * 512 + f8 * 8];
        float4 a = p[0], b = p[1];
        half8 h;
        h[0] = (_Float16)(a.x * w); h[1] = (_Float16)(a.y * w);
        h[2] = (_Float16)(a.z * w); h[3] = (_Float16)(a.w * w);
        h[4] = (_Float16)(b.x * w); h[5] = (_Float16)(b.y * w);
        h[6] = (_Float16)(b.z * w); h[7] = (_Float16)(b.w * w);
        int q = f8 >> 4, fl8 = f8 & 15;
        *(half8*)&xs[(size_t)q * QSTRIDE + (size_t)node * 128 + fl8 * 8] = h;
    } else {
        int wb = bid - 2500;                      // [0, 384): 128 blocks per W
        int which = wb >> 7;
        const float* W = which == 0 ? W1 : (which == 1 ? W2 : W3);
        size_t mbase = (size_t)which * 262144;
        int chunk = (wb & 127) * 256 + threadIdx.x;   // 0..32767
        int i = chunk & 63;
        int kb = (chunk >> 6) & 15;
        int s = chunk >> 10;
        int n = s * 16 + (i & 15);
        int k0 = kb * 32 + (i >> 4) * 8;
        half8 h8;
#pragma unroll
        for (int j = 0; j < 8; j++)
            h8[j] = (_Float16)W[(size_t)(k0 + j) * 512 + n];
        *(half8*)&wt[mbase + (size_t)chunk * 8] = h8;
    }
}

// ---------------- aggregation v11 (R13-proven): fma_mix, 16-lane groups ----------------
__global__ __launch_bounds__(256) void agg_kernel(const _Float16* __restrict__ xs,
        const int* __restrict__ edge_src, const int* __restrict__ row_ptr,
        const float* __restrict__ norm_in, _Float16* __restrict__ a_t) {
    int bid = blockIdx.x;
    int xcd = bid & 7;
    int q = xcd >> 1;
    int idx = ((bid >> 3) << 1) | (xcd & 1);      // block index within quarter [0,628)
    int grp = threadIdx.x >> 4;                   // group 0..15 -> node
    int fl = threadIdx.x & 15;                    // 16B feature slice within quarter
    int d = idx * 16 + grp;
    const _Float16* xq = xs + (size_t)q * QSTRIDE + fl * 8;

    float acc[8] = {};
    if (d < N_NODES) {
        int beg = row_ptr[d], end = row_ptr[d + 1];
        float ni = norm_in[d];                    // prefetch: overlaps edge loop
        float one = 1.0f;
        int e = beg;
        for (; e + 3 < end; e += 4) {             // 4 edges in flight per group
            int s0 = edge_src[e],     s1 = edge_src[e + 1];
            int s2 = edge_src[e + 2], s3 = edge_src[e + 3];
            uint4 u0 = *(const uint4*)&xq[(size_t)s0 * 128];
            uint4 u1 = *(const uint4*)&xq[(size_t)s1 * 128];
            uint4 u2 = *(const uint4*)&xq[(size_t)s2 * 128];
            uint4 u3 = *(const uint4*)&xq[(size_t)s3 * 128];
            acc_mix(acc, u0, one);
            acc_mix(acc, u1, one);
            acc_mix(acc, u2, one);
            acc_mix(acc, u3, one);
        }
        for (; e < end; e++) {
            int s = edge_src[e];
            uint4 u = *(const uint4*)&xq[(size_t)s * 128];
            acc_mix(acc, u, one);
        }
#pragma unroll
        for (int i = 0; i < 8; i++) acc[i] *= ni;
    }
    // every lane writes its 16B slice; pad rows (>= N_NODES) get zeros
    half8 h8;
#pragma unroll
    for (int i = 0; i < 8; i++) h8[i] = (_Float16)acc[i];
    // tiled A layout: k0 = q*128 + fl*8 -> kb = q*4 + (fl>>2), kq = fl&3
    size_t o = (size_t)(d >> 4) * 8192 + (size_t)(q * 4 + (fl >> 2)) * 512
             + (size_t)((fl & 3) * 16 + (d & 15)) * 8;
    *(half8*)&a_t[o] = h8;
}

// ---------------- fp16 MFMA GEMM, BK=64 (R8 latency-count-driven) ----------------
// BM=64, BN=128, BK=64; 4 waves, wave tile 32x64. LDS 8+16=24 KB. 8 K-iters
// (was 16): halves the serial stage->drain->compute round trips that R8
// measured at ~600ns each (R12 proved source-level overlap is impossible --
// compiler drains vmcnt(0) at every barrier -- so fewer/fatter trips is the
// remaining lever). Per wave per iter: 6 gload_lds + 12 ds_read_b128 + 16 MFMA.
// LDS layout: strip-major, 2 k-blocks per strip: tile (s, j) at (s*2+j)*512.
// Dual-output on columns >= 512 (block-uniform): Cb / bias_b / RELU_B.
template <bool RELU_A, bool RELU_B, bool WRITE_C, bool WRITE_XS>
__global__ __launch_bounds__(256) void mfma_gemm(
        const _Float16* __restrict__ A_t, const _Float16* __restrict__ Bt,
        const float* __restrict__ bias_a, const float* __restrict__ bias_b,
        const float* __restrict__ norm_out,
        float* __restrict__ Ca, float* __restrict__ Cb,
        _Float16* __restrict__ xs) {
    __shared__ __align__(16) _Float16 lsA[64 * 64];       // 4 strips x 2 kb: 8 KB
    __shared__ __align__(16) _Float16 lsB[128 * 64];      // 8 strips x 2 kb: 16 KB
    int tid = threadIdx.x;
    int w = tid >> 6, lane = tid & 63;
    int col0 = blockIdx.x * 128;
    int row0 = blockIdx.y * 64;
    int wm = w & 1, wn = w >> 1;
    int lr = lane & 15, lq = lane >> 4;

    size_t aoff = (size_t)((row0 >> 4) + w) * 8192 + lane * 8;       // A strip w
    size_t boff = (size_t)((col0 >> 4) + 2 * w) * 8192 + lane * 8;   // B strips 2w, 2w+1
    _Float16* dA0 = &lsA[(w * 2) * 512 + lane * 8];
    _Float16* dA1 = dA0 + 512;
    _Float16* dB0 = &lsB[((2 * w) * 2) * 512 + lane * 8];
    _Float16* dB1 = dB0 + 512;
    _Float16* dB2 = &lsB[((2 * w + 1) * 2) * 512 + lane * 8];
    _Float16* dB3 = dB2 + 512;

    f32x4 acc[2][4] = {};

    for (int kb = 0; kb < 8; kb++) {
        size_t ko = (size_t)kb * 1024;            // 2 k-blocks per iter
        load_lds16(A_t + aoff + ko, dA0);
        load_lds16(A_t + aoff + ko + 512, dA1);
        load_lds16(Bt + boff + ko, dB0);
        load_lds16(Bt + boff + ko + 512, dB1);
        load_lds16(Bt + boff + 8192 + ko, dB2);
        load_lds16(Bt + boff + 8192 + ko + 512, dB3);
        __syncthreads();

#pragma unroll
        for (int kk = 0; kk < 2; kk++) {
            half8 a[2], b[4];
#pragma unroll
            for (int i = 0; i < 2; i++)
                a[i] = *(const half8*)&lsA[((wm * 2 + i) * 2 + kk) * 512 + lane * 8];
#pragma unroll
            for (int j = 0; j < 4; j++)
                b[j] = *(const half8*)&lsB[((wn * 4 + j) * 2 + kk) * 512 + lane * 8];
#pragma unroll
            for (int i = 0; i < 2; i++)
#pragma unroll
                for (int j = 0; j < 4; j++)
                    acc[i][j] = __builtin_amdgcn_mfma_f32_16x16x32_f16(a[i], b[j], acc[i][j], 0, 0, 0);
        }
        __syncthreads();
    }

    bool sec = (col0 >= 512);                 // block-uniform
    const float* bias = sec ? bias_b : bias_a;
    float* C = sec ? Cb : Ca;
    int cb0 = sec ? col0 - 512 : col0;
    const bool relu = sec ? RELU_B : RELU_A;

#pragma unroll
    for (int i = 0; i < 2; i++)
#pragma unroll
        for (int j = 0; j < 4; j++) {
            int col = cb0 + wn * 64 + j * 16 + lr;
            float bv = bias[col];
#pragma unroll
            for (int r = 0; r < 4; r++) {
                int row = row0 + wm * 32 + i * 16 + lq * 4 + r;
                if (row < N_NODES) {
                    float v = acc[i][j][r] + bv;
                    if (relu) v = fmaxf(v, 0.f);
                    if (WRITE_C) C[(size_t)row * 512 + col] = v;
                    if (WRITE_XS) {
                        int q = col >> 7, f = col & 127;
                        xs[(size_t)q * QSTRIDE + (size_t)row * 128 + f] =
                            (_Float16)(v * norm_out[row]);
                    }
                }
            }
        }
}

extern "C" void kernel_launch(void* const* d_in, const int* in_sizes, int n_in,
                              void* d_out, int out_size, void* d_ws, size_t ws_size,
                              hipStream_t stream) {
    const float* x  = (const float*)d_in[0];
    const float* W1 = (const float*)d_in[1];
    const float* b1 = (const float*)d_in[2];
    const float* W2 = (const float*)d_in[3];
    const float* b2 = (const float*)d_in[4];
    const float* W3 = (const float*)d_in[5];
    const float* b3 = (const float*)d_in[6];
    const int* src  = (const int*)d_in[7];
    const int* dst  = (const int*)d_in[8];
    float* out = (float*)d_out;

    // workspace layout
    int* wsi = (int*)d_ws;
    int* deg_out  = wsi;                       // 10000
    int* deg_in   = wsi + 10000;               // 10000
    float* norm_out = (float*)(wsi + 20000);   // 10000
    float* norm_in  = (float*)(wsi + 30000);   // 10000
    int* row_ptr  = wsi + 40000;               // 10001 (pad to 10016)
    int* cursor   = wsi + 50016;               // 10000
    int* bsum     = wsi + 60016;               // 40 (pad to 48)
    int* edge_src = wsi + 60064;               // 160000  -> ends at int 220064
    _Float16* wt  = (_Float16*)(wsi + 220064);         // 3 * 262144 halves (tiled)
    _Float16* a_t = wt + 786432;                       // M_PAD * 512 (tiled)
    _Float16* xs  = a_t + (size_t)M_PAD * 512;         // 4 * QSTRIDE (quarter-major)
    // total ~23 MB

    // d_out layout: [h4 | h3 | h2]
    float* h4 = out;
    float* h3 = out + 5120000;
    float* h2 = out + 10240000;

    hipMemsetAsync(d_ws, 0, 20000 * sizeof(int), stream);  // deg_out + deg_in

    deg_kernel<<<(N_EDGES + 255) / 256, 256, 0, stream>>>(src, dst, deg_out, deg_in);
    scan1_kernel<<<40, 256, 0, stream>>>(deg_in, deg_out, row_ptr, bsum, norm_out, norm_in);
    scan2_kernel<<<40, 256, 0, stream>>>(bsum, row_ptr, cursor);
    fill_kernel<<<(N_EDGES + 255) / 256, 256, 0, stream>>>(src, dst, cursor, edge_src);
    prep_kernel<<<2884, 256, 0, stream>>>(x, norm_out, xs, W1, W2, W3, wt);

    _Float16* wt1 = wt;
    _Float16* wt2 = wt + 262144;   // W2^T | W3^T contiguous for the fused GEMM

    dim3 ga(2512);            // agg: 16 nodes/block, XCD-pinned quarters
    dim3 g1(4, M_PAD / 64);   // N = 512   (col-blocks fast -> A-panel reuse)
    dim3 g2(8, M_PAD / 64);   // N = 1024  (fused h3|h4)

    // layer 1: h1 never materialized in fp32 — GEMM writes xs only
    agg_kernel<<<ga, 256, 0, stream>>>(xs, edge_src, row_ptr, norm_in, a_t);
    mfma_gemm<true, true, false, true><<<g1, 256, 0, stream>>>(
        a_t, wt1, b1, b1, norm_out, h2, h2, xs);
    // layer 2: h2 is an output AND feeds agg3 via xs
    agg_kernel<<<ga, 256, 0, stream>>>(xs, edge_src, row_ptr, norm_in, a_t);
    mfma_gemm<true, true, true, true><<<g1, 256, 0, stream>>>(
        a_t, wt2, b2, b2, norm_out, h2, h2, xs);
    // layers 3 & 4 share the aggregation of h2; one fused N=1024 GEMM
    agg_kernel<<<ga, 256, 0, stream>>>(xs, edge_src, row_ptr, norm_in, a_t);
    mfma_gemm<true, false, true, false><<<g2, 256, 0, stream>>>(
        a_t, wt2, b2, b3, norm_out, h3, h4, xs);
}

// Round 16
// 233.542 us; speedup vs baseline: 1.0037x; 1.0037x over previous
//
#include <hip/hip_runtime.h>

#define N_NODES 10000
#define N_EDGES 160000
#define FEAT 512
#define M_PAD 10048        // 157 * 64  (GEMM BM=64)
#define QSTRIDE 1286144    // xs quarter stride in halves: 10048 * 128

typedef unsigned int uint32;

typedef __attribute__((ext_vector_type(8))) _Float16 half8;     // 16 B = MFMA A/B frag
typedef __attribute__((ext_vector_type(4))) float f32x4;        // MFMA C/D

// ---- tiled ("fragment order") fp16 layout for a R x 512 matrix ----
// strip s = row>>4 (16 rows), k-block kb = k>>5 (32 k). Each (s,kb) is a 1 KB
// tile; half-elem offset = s*8192 + kb*512 + (kq*16 + (row&15))*8 + (k&7),
// kq = (k>>3)&3.
//
// ---- quarter-major xs layout (gather source) ----
// xs[q*QSTRIDE + node*128 + f], q = feat>>7, f = feat&127. Agg pins quarter q
// to XCD pair {2q, 2q+1}.
//
// Config ledger (measured totals): R13 = 234.1 (best -> THIS config);
// R14 BK=64 = 234.4; R11 = 235.3; R6 = 236.0; R7 = 238.1; R12 dbuf = 240.3
// (compiler drains vmcnt(0) at every barrier -> no overlap); R10 BN=64 =
// 246.3; R15 cooperative mega-kernel = container failure (hipLaunch-
// CooperativeKernel under graph capture is unsupported -> DO NOT RETRY).
// R9 probe: agg = VALU/divergence-bound (50% VALU, 8.7% HBM, 0 conflicts).
// R8 probe: GEMM latency-bound (8% MfmaUtil, 14% occupancy, grid-limited;
// tile/pipeline variants all within noise).

__device__ __forceinline__ void load_lds16(const void* g, void* l) {
    __builtin_amdgcn_global_load_lds(
        (const __attribute__((address_space(1))) void*)g,
        (__attribute__((address_space(3))) void*)l, 16, 0, 0);
}

// acc[i] += f16[i] for 8 packed halves in a uint4, one v_fma_mix_f32 each.
// op_sel_hi:[1,0,0] marks src0 as f16 (lo half; op_sel:[1,..] picks hi half).
__device__ __forceinline__ void acc_mix(float (&acc)[8], uint4 u, float one) {
    asm("v_fma_mix_f32 %0, %8, %9, %0 op_sel_hi:[1,0,0]\n\t"
        "v_fma_mix_f32 %1, %8, %9, %1 op_sel:[1,0,0] op_sel_hi:[1,0,0]\n\t"
        "v_fma_mix_f32 %2, %10, %9, %2 op_sel_hi:[1,0,0]\n\t"
        "v_fma_mix_f32 %3, %10, %9, %3 op_sel:[1,0,0] op_sel_hi:[1,0,0]\n\t"
        "v_fma_mix_f32 %4, %11, %9, %4 op_sel_hi:[1,0,0]\n\t"
        "v_fma_mix_f32 %5, %11, %9, %5 op_sel:[1,0,0] op_sel_hi:[1,0,0]\n\t"
        "v_fma_mix_f32 %6, %12, %9, %6 op_sel_hi:[1,0,0]\n\t"
        "v_fma_mix_f32 %7, %12, %9, %7 op_sel:[1,0,0] op_sel_hi:[1,0,0]"
        : "+v"(acc[0]), "+v"(acc[1]), "+v"(acc[2]), "+v"(acc[3]),
          "+v"(acc[4]), "+v"(acc[5]), "+v"(acc[6]), "+v"(acc[7])
        : "v"(u.x), "v"(one), "v"(u.y), "v"(u.z), "v"(u.w));
}

// ---------------- degree count ----------------
__global__ void deg_kernel(const int* __restrict__ src, const int* __restrict__ dst,
                           int* __restrict__ deg_out, int* __restrict__ deg_in) {
    int e = blockIdx.x * blockDim.x + threadIdx.x;
    if (e < N_EDGES) {
        atomicAdd(&deg_out[src[e]], 1);
        atomicAdd(&deg_in[dst[e]], 1);
    }
}

// ---------------- scan phase 1: per-block exclusive scan + norms ----------------
__global__ __launch_bounds__(256) void scan1_kernel(const int* __restrict__ deg_in,
        const int* __restrict__ deg_out, int* __restrict__ row_ptr,
        int* __restrict__ bsum, float* __restrict__ norm_out, float* __restrict__ norm_in) {
    __shared__ int s[256];
    int t = threadIdx.x, b = blockIdx.x;
    int i = b * 256 + t;
    int v = (i < N_NODES) ? deg_in[i] : 0;
    s[t] = v;
    __syncthreads();
    for (int off = 1; off < 256; off <<= 1) {
        int x = (t >= off) ? s[t - off] : 0;
        __syncthreads();
        s[t] += x;
        __syncthreads();
    }
    if (i < N_NODES) {
        row_ptr[i] = s[t] - v;                 // block-local exclusive prefix
        int dob = deg_out[i];
        norm_in[i]  = v   > 0 ? rsqrtf((float)v)   : 0.f;
        norm_out[i] = dob > 0 ? rsqrtf((float)dob) : 0.f;
    }
    if (t == 255) bsum[b] = s[255];
}

// ---------------- scan phase 2: add block offsets ----------------
__global__ __launch_bounds__(256) void scan2_kernel(const int* __restrict__ bsum,
        int* __restrict__ row_ptr, int* __restrict__ cursor) {
    int t = threadIdx.x, b = blockIdx.x;
    int i = b * 256 + t;
    int off = 0;
    for (int j = 0; j < b; j++) off += bsum[j];   // uniform, <=39 L2-hot scalar loads
    if (i < N_NODES) {
        int r = row_ptr[i] + off;
        row_ptr[i] = r;
        cursor[i] = r;
    }
    if (b == 0 && t == 0) row_ptr[N_NODES] = N_EDGES;   // degrees sum to edge count
}

// ---------------- CSR fill ----------------
__global__ void fill_kernel(const int* __restrict__ src, const int* __restrict__ dst,
                            int* __restrict__ cursor, int* __restrict__ edge_src) {
    int e = blockIdx.x * blockDim.x + threadIdx.x;
    if (e < N_EDGES) {
        int d = dst[e];
        int pos = atomicAdd(&cursor[d], 1);
        edge_src[pos] = src[e];
    }
}

// ---------------- merged prep: prescale (blocks 0..2499) + wsplit (2500..2883) ----------------
__global__ __launch_bounds__(256) void prep_kernel(const float* __restrict__ x,
        const float* __restrict__ norm_out, _Float16* __restrict__ xs,
        const float* __restrict__ W1, const float* __restrict__ W2,
        const float* __restrict__ W3, _Float16* __restrict__ wt) {
    int bid = blockIdx.x;
    if (bid < 2500) {
        int idx = bid * 256 + threadIdx.x;        // one per 8 floats; 2500*256 = 640000 exact
        int node = idx >> 6, f8 = idx & 63;
        float w = norm_out[node];
        const float4* p = (const float4*)&x[(size_t)node * 512 + f8 * 8];
        float4 a = p[0], b = p[1];
        half8 h;
        h[0] = (_Float16)(a.x * w); h[1] = (_Float16)(a.y * w);
        h[2] = (_Float16)(a.z * w); h[3] = (_Float16)(a.w * w);
        h[4] = (_Float16)(b.x * w); h[5] = (_Float16)(b.y * w);
        h[6] = (_Float16)(b.z * w); h[7] = (_Float16)(b.w * w);
        int q = f8 >> 4, fl8 = f8 & 15;
        *(half8*)&xs[(size_t)q * QSTRIDE + (size_t)node * 128 + fl8 * 8] = h;
    } else {
        int wb = bid - 2500;                      // [0, 384): 128 blocks per W
        int which = wb >> 7;
        const float* W = which == 0 ? W1 : (which == 1 ? W2 : W3);
        size_t mbase = (size_t)which * 262144;
        int chunk = (wb & 127) * 256 + threadIdx.x;   // 0..32767
        int i = chunk & 63;
        int kb = (chunk >> 6) & 15;
        int s = chunk >> 10;
        int n = s * 16 + (i & 15);
        int k0 = kb * 32 + (i >> 4) * 8;
        half8 h8;
#pragma unroll
        for (int j = 0; j < 8; j++)
            h8[j] = (_Float16)W[(size_t)(k0 + j) * 512 + n];
        *(half8*)&wt[mbase + (size_t)chunk * 8] = h8;
    }
}

// ---------------- aggregation v11 (R13-proven): fma_mix, 16-lane groups ----------------
// 2512 blocks x 256 threads; 16 consecutive nodes per block (one a_t strip-
// quarter, contiguous 4KB writes), 4 independent gather chains per wave, no
// cross-lane reduce, every lane writes its 16 B slice. XCD-pin: bid&7 ->
// quarter q = xcd>>1 stays on XCD pair {2q, 2q+1}; parity bijection.
__global__ __launch_bounds__(256) void agg_kernel(const _Float16* __restrict__ xs,
        const int* __restrict__ edge_src, const int* __restrict__ row_ptr,
        const float* __restrict__ norm_in, _Float16* __restrict__ a_t) {
    int bid = blockIdx.x;
    int xcd = bid & 7;
    int q = xcd >> 1;
    int idx = ((bid >> 3) << 1) | (xcd & 1);      // block index within quarter [0,628)
    int grp = threadIdx.x >> 4;                   // group 0..15 -> node
    int fl = threadIdx.x & 15;                    // 16B feature slice within quarter
    int d = idx * 16 + grp;
    const _Float16* xq = xs + (size_t)q * QSTRIDE + fl * 8;

    float acc[8] = {};
    if (d < N_NODES) {
        int beg = row_ptr[d], end = row_ptr[d + 1];
        float ni = norm_in[d];                    // prefetch: overlaps edge loop
        float one = 1.0f;
        int e = beg;
        for (; e + 3 < end; e += 4) {             // 4 edges in flight per group
            int s0 = edge_src[e],     s1 = edge_src[e + 1];
            int s2 = edge_src[e + 2], s3 = edge_src[e + 3];
            uint4 u0 = *(const uint4*)&xq[(size_t)s0 * 128];
            uint4 u1 = *(const uint4*)&xq[(size_t)s1 * 128];
            uint4 u2 = *(const uint4*)&xq[(size_t)s2 * 128];
            uint4 u3 = *(const uint4*)&xq[(size_t)s3 * 128];
            acc_mix(acc, u0, one);
            acc_mix(acc, u1, one);
            acc_mix(acc, u2, one);
            acc_mix(acc, u3, one);
        }
        for (; e < end; e++) {
            int s = edge_src[e];
            uint4 u = *(const uint4*)&xq[(size_t)s * 128];
            acc_mix(acc, u, one);
        }
#pragma unroll
        for (int i = 0; i < 8; i++) acc[i] *= ni;
    }
    // every lane writes its 16B slice; pad rows (>= N_NODES) get zeros
    half8 h8;
#pragma unroll
    for (int i = 0; i < 8; i++) h8[i] = (_Float16)acc[i];
    // tiled A layout: k0 = q*128 + fl*8 -> kb = q*4 + (fl>>2), kq = fl&3
    size_t o = (size_t)(d >> 4) * 8192 + (size_t)(q * 4 + (fl >> 2)) * 512
             + (size_t)((fl & 3) * 16 + (d & 15)) * 8;
    *(half8*)&a_t[o] = h8;
}

// ---------------- 1-term fp16 MFMA GEMM, tiled inputs (R13-proven) ----------------
// C = A(M_PAD x 512) @ W(512 x N) + bias.  BM=64, BN=128, BK=32; 4 waves,
// wave tile 32x64 (2x4 16x16x32 f16 MFMA). LDS 12 KB. 628/1256 blocks.
// BM=128 regressed twice (R1, R4); dbuf regressed (R12); BK=64 neutral (R14).
// WRITE_C: store fp32 C.  WRITE_XS: store xs = fp16(out*norm_out), quarter-major.
// Dual-output on columns >= 512 (block-uniform): Cb / bias_b / RELU_B.
template <bool RELU_A, bool RELU_B, bool WRITE_C, bool WRITE_XS>
__global__ __launch_bounds__(256) void mfma_gemm(
        const _Float16* __restrict__ A_t, const _Float16* __restrict__ Bt,
        const float* __restrict__ bias_a, const float* __restrict__ bias_b,
        const float* __restrict__ norm_out,
        float* __restrict__ Ca, float* __restrict__ Cb,
        _Float16* __restrict__ xs) {
    __shared__ __align__(16) _Float16 lsA[64 * 32];       // 4 strips: 4 KB
    __shared__ __align__(16) _Float16 lsB[128 * 32];      // 8 strips: 8 KB
    int tid = threadIdx.x;
    int w = tid >> 6, lane = tid & 63;
    int col0 = blockIdx.x * 128;
    int row0 = blockIdx.y * 64;
    int wm = w & 1, wn = w >> 1;
    int lr = lane & 15, lq = lane >> 4;

    size_t aoff = (size_t)((row0 >> 4) + w) * 8192 + lane * 8;
    size_t boff = (size_t)((col0 >> 4) + 2 * w) * 8192 + lane * 8;
    _Float16* dA  = &lsA[(w * 64 + lane) * 8];
    _Float16* dB0 = &lsB[((2 * w) * 64 + lane) * 8];
    _Float16* dB1 = &lsB[((2 * w + 1) * 64 + lane) * 8];

    f32x4 acc[2][4] = {};

    for (int kb = 0; kb < 16; kb++) {
        size_t ko = (size_t)kb * 512;
        load_lds16(A_t + aoff + ko, dA);
        load_lds16(Bt + boff + ko, dB0);
        load_lds16(Bt + boff + 8192 + ko, dB1);
        __syncthreads();

        half8 a[2], b[4];
#pragma unroll
        for (int i = 0; i < 2; i++)
            a[i] = *(const half8*)&lsA[((wm * 2 + i) * 64 + lane) * 8];
#pragma unroll
        for (int j = 0; j < 4; j++)
            b[j] = *(const half8*)&lsB[((wn * 4 + j) * 64 + lane) * 8];
#pragma unroll
        for (int i = 0; i < 2; i++)
#pragma unroll
            for (int j = 0; j < 4; j++)
                acc[i][j] = __builtin_amdgcn_mfma_f32_16x16x32_f16(a[i], b[j], acc[i][j], 0, 0, 0);
        __syncthreads();
    }

    bool sec = (col0 >= 512);                 // block-uniform
    const float* bias = sec ? bias_b : bias_a;
    float* C = sec ? Cb : Ca;
    int cb0 = sec ? col0 - 512 : col0;
    const bool relu = sec ? RELU_B : RELU_A;

#pragma unroll
    for (int i = 0; i < 2; i++)
#pragma unroll
        for (int j = 0; j < 4; j++) {
            int col = cb0 + wn * 64 + j * 16 + lr;
            float bv = bias[col];
#pragma unroll
            for (int r = 0; r < 4; r++) {
                int row = row0 + wm * 32 + i * 16 + lq * 4 + r;
                if (row < N_NODES) {
                    float v = acc[i][j][r] + bv;
                    if (relu) v = fmaxf(v, 0.f);
                    if (WRITE_C) C[(size_t)row * 512 + col] = v;
                    if (WRITE_XS) {
                        int q = col >> 7, f = col & 127;
                        xs[(size_t)q * QSTRIDE + (size_t)row * 128 + f] =
                            (_Float16)(v * norm_out[row]);
                    }
                }
            }
        }
}

extern "C" void kernel_launch(void* const* d_in, const int* in_sizes, int n_in,
                              void* d_out, int out_size, void* d_ws, size_t ws_size,
                              hipStream_t stream) {
    const float* x  = (const float*)d_in[0];
    const float* W1 = (const float*)d_in[1];
    const float* b1 = (const float*)d_in[2];
    const float* W2 = (const float*)d_in[3];
    const float* b2 = (const float*)d_in[4];
    const float* W3 = (const float*)d_in[5];
    const float* b3 = (const float*)d_in[6];
    const int* src  = (const int*)d_in[7];
    const int* dst  = (const int*)d_in[8];
    float* out = (float*)d_out;

    // workspace layout
    int* wsi = (int*)d_ws;
    int* deg_out  = wsi;                       // 10000
    int* deg_in   = wsi + 10000;               // 10000
    float* norm_out = (float*)(wsi + 20000);   // 10000
    float* norm_in  = (float*)(wsi + 30000);   // 10000
    int* row_ptr  = wsi + 40000;               // 10001 (pad to 10016)
    int* cursor   = wsi + 50016;               // 10000
    int* bsum     = wsi + 60016;               // 40 (pad to 48)
    int* edge_src = wsi + 60064;               // 160000  -> ends at int 220064
    _Float16* wt  = (_Float16*)(wsi + 220064);         // 3 * 262144 halves (tiled)
    _Float16* a_t = wt + 786432;                       // M_PAD * 512 (tiled)
    _Float16* xs  = a_t + (size_t)M_PAD * 512;         // 4 * QSTRIDE (quarter-major)
    // total ~23 MB

    // d_out layout: [h4 | h3 | h2]
    float* h4 = out;
    float* h3 = out + 5120000;
    float* h2 = out + 10240000;

    hipMemsetAsync(d_ws, 0, 20000 * sizeof(int), stream);  // deg_out + deg_in

    deg_kernel<<<(N_EDGES + 255) / 256, 256, 0, stream>>>(src, dst, deg_out, deg_in);
    scan1_kernel<<<40, 256, 0, stream>>>(deg_in, deg_out, row_ptr, bsum, norm_out, norm_in);
    scan2_kernel<<<40, 256, 0, stream>>>(bsum, row_ptr, cursor);
    fill_kernel<<<(N_EDGES + 255) / 256, 256, 0, stream>>>(src, dst, cursor, edge_src);
    prep_kernel<<<2884, 256, 0, stream>>>(x, norm_out, xs, W1, W2, W3, wt);

    _Float16* wt1 = wt;
    _Float16* wt2 = wt + 262144;   // W2^T | W3^T contiguous for the fused GEMM

    dim3 ga(2512);            // agg: 16 nodes/block, XCD-pinned quarters
    dim3 g1(4, M_PAD / 64);   // N = 512   (col-blocks fast -> A-panel reuse)
    dim3 g2(8, M_PAD / 64);   // N = 1024  (fused h3|h4)

    // layer 1: h1 never materialized in fp32 — GEMM writes xs only
    agg_kernel<<<ga, 256, 0, stream>>>(xs, edge_src, row_ptr, norm_in, a_t);
    mfma_gemm<true, true, false, true><<<g1, 256, 0, stream>>>(
        a_t, wt1, b1, b1, norm_out, h2, h2, xs);
    // layer 2: h2 is an output AND feeds agg3 via xs
    agg_kernel<<<ga, 256, 0, stream>>>(xs, edge_src, row_ptr, norm_in, a_t);
    mfma_gemm<true, true, true, true><<<g1, 256, 0, stream>>>(
        a_t, wt2, b2, b2, norm_out, h2, h2, xs);
    // layers 3 & 4 share the aggregation of h2; one fused N=1024 GEMM
    agg_kernel<<<ga, 256, 0, stream>>>(xs, edge_src, row_ptr, norm_in, a_t);
    mfma_gemm<true, false, true, false><<<g2, 256, 0, stream>>>(
        a_t, wt2, b2, b3, norm_out, h3, h4, xs);
}